// Round 7
// baseline (118.251 us; speedup 1.0000x reference)
//
#include <hip/hip_runtime.h>
#include <hip/hip_fp16.h>
#include <math.h>
#include <float.h>

#define SET_SIZE 8
#define EMB_DIM 64
#define NPAIR 36
#define NDOT (SET_SIZE + NPAIR)

typedef _Float16 f16x2 __attribute__((ext_vector_type(2)));
typedef float    vf4   __attribute__((ext_vector_type(4)));
typedef float    vf2   __attribute__((ext_vector_type(2)));
typedef int      vi4   __attribute__((ext_vector_type(4)));

union Frag32 {
    float4 f4[2];   // two 16B raw loads (32B = 16 fp16)
    f16x2  h2[8];   // 16 fp16 elements
};

__device__ __forceinline__ float dot16_f16(const Frag32& a, const Frag32& b) {
    float c = 0.0f;
#pragma unroll
    for (int j = 0; j < 8; ++j)
        c = __builtin_amdgcn_fdot2(a.h2[j], b.h2[j], c, false);
    return c;
}

// Quad reduce via DPP quad_perm (pure VALU, no LDS pipe).
__device__ __forceinline__ float quad_reduce_add(float x) {
    int t = __builtin_amdgcn_update_dpp(0, __float_as_int(x), 0xB1, 0xF, 0xF, true);
    x += __int_as_float(t);
    t = __builtin_amdgcn_update_dpp(0, __float_as_int(x), 0x4E, 0xF, 0xF, true);
    x += __int_as_float(t);
    return x;
}

// Fused f32 -> f16 conversion for both tables; 8 floats per thread.
__global__ __launch_bounds__(256) void cvt_both_kernel(
    const float* __restrict__ a, const float* __restrict__ b,
    __half* __restrict__ oa, __half* __restrict__ ob, int n8a, int n8b)
{
    int i = blockIdx.x * blockDim.x + threadIdx.x;
    const float* in;
    __half* out;
    int j;
    if (i < n8a) { in = a; out = oa; j = i; }
    else if (i < n8a + n8b) { in = b; out = ob; j = i - n8a; }
    else return;
    const vf4* p = (const vf4*)in + 2 * (size_t)j;
    vf4 x = __builtin_nontemporal_load(p);
    vf4 y = __builtin_nontemporal_load(p + 1);
    union { __half2 h2[4]; vf4 f4; } u;
    u.h2[0] = __floats2half2_rn(x.x, x.y);
    u.h2[1] = __floats2half2_rn(x.z, x.w);
    u.h2[2] = __floats2half2_rn(y.x, y.y);
    u.h2[3] = __floats2half2_rn(y.z, y.w);
    ((vf4*)out)[j] = u.f4;
}

// 4 lanes per candidate, grid-stride over candidates with next-iteration
// X/h prefetch so the index load's round-trip is off the critical path.
// X/h/out use nontemporal hints: they're touched once, and shouldn't evict
// embedding-table lines from L2 (the kernel is L2-request-throughput bound).
__global__ __launch_bounds__(256, 4) void hyperedge_score_q4(
    const __half* __restrict__ node_f16,   // [N_NODES, 64]
    const __half* __restrict__ he_f16,     // [N_HYPEREDGES, 64]
    const int*    __restrict__ h,          // [E]
    const int*    __restrict__ X,          // [E, 8]
    float*        __restrict__ out,        // [E, 2]
    int n_cand)
{
    int tid  = blockIdx.x * blockDim.x + threadIdx.x;
    int grp  = tid >> 2;                   // starting candidate
    int q    = tid & 3;                    // lane within quad
    int quads = (gridDim.x * blockDim.x) >> 2;  // grid-stride in candidates

    if (grp >= n_cand) return;

    // Prefetch first candidate's indices.
    vi4 nx0 = __builtin_nontemporal_load((const vi4*)(X + (size_t)grp * SET_SIZE));
    vi4 nx1 = __builtin_nontemporal_load((const vi4*)(X + (size_t)grp * SET_SIZE) + 1);
    int nhe = h[grp];

    for (int c = grp; c < n_cand; c += quads) {
        vi4 x0 = nx0, x1 = nx1;
        int he = nhe;
        int idx[SET_SIZE] = {x0.x, x0.y, x0.z, x0.w, x1.x, x1.y, x1.z, x1.w};

        // Issue the 18 row loads.
        Frag32 v[9];
#pragma unroll
        for (int r = 0; r < SET_SIZE; ++r) {
            const float4* p = (const float4*)(node_f16 + (size_t)idx[r] * EMB_DIM);
            v[r].f4[0] = p[q];
            v[r].f4[1] = p[q + 4];
        }
        {
            const float4* p = (const float4*)(he_f16 + (size_t)he * EMB_DIM);
            v[8].f4[0] = p[q];
            v[8].f4[1] = p[q + 4];
        }

        // Prefetch next candidate's indices while rows are in flight.
        int cn = c + quads;
        if (cn < n_cand) {
            nx0 = __builtin_nontemporal_load((const vi4*)(X + (size_t)cn * SET_SIZE));
            nx1 = __builtin_nontemporal_load((const vi4*)(X + (size_t)cn * SET_SIZE) + 1);
            nhe = h[cn];
        }

        // Star dots: immediate quad-reduce + min-fold.
        float smin = FLT_MAX;
#pragma unroll
        for (int s = 0; s < SET_SIZE; ++s) {
            float d = quad_reduce_add(dot16_f16(v[8], v[s]));
            smin = fminf(smin, d);
        }

        // Pair dots (upper triangle incl diagonal).
        float pmin = FLT_MAX;
#pragma unroll
        for (int s = 0; s < SET_SIZE; ++s) {
#pragma unroll
            for (int t = s; t < SET_SIZE; ++t) {
                float d = quad_reduce_add(dot16_f16(v[s], v[t]));
                pmin = fminf(pmin, d);
            }
        }

        // sigmoid is monotonic: min(sigmoid(x)) == sigmoid(min(x)).
        float star_sig   = 1.0f / (1.0f + __expf(-smin));
        float clique_sig = 1.0f / (1.0f + __expf(-pmin));
        if (q == 0) {
            vf2 res;
            res.x = star_sig;
            res.y = clique_sig;
            __builtin_nontemporal_store(res, (vf2*)(out + (size_t)c * 2));
        }
    }
}

// ---- f32 fallback (R2 structure) if workspace is too small ----
__device__ __forceinline__ float dot4f(float4 a, float4 b) {
    return fmaf(a.x, b.x, fmaf(a.y, b.y, fmaf(a.z, b.z, a.w * b.w)));
}

__global__ __launch_bounds__(256) void hyperedge_score_f32(
    const float* __restrict__ node_emb, const float* __restrict__ hyperedge_emb,
    const int* __restrict__ h, const int* __restrict__ X,
    float* __restrict__ out, int n_cand)
{
    int tid = blockIdx.x * blockDim.x + threadIdx.x;
    int grp = tid >> 3;
    int q   = tid & 7;
    if (grp >= n_cand) return;
    const int4* Xv = (const int4*)(X + (size_t)grp * SET_SIZE);
    int4 x0 = Xv[0]; int4 x1 = Xv[1];
    int he = h[grp];
    int idx[SET_SIZE] = {x0.x, x0.y, x0.z, x0.w, x1.x, x1.y, x1.z, x1.w};
    float4 va[9], vb[9];
#pragma unroll
    for (int r = 0; r < SET_SIZE; ++r) {
        const float4* p = (const float4*)(node_emb + (size_t)idx[r] * EMB_DIM) + 2 * q;
        va[r] = p[0]; vb[r] = p[1];
    }
    {
        const float4* p = (const float4*)(hyperedge_emb + (size_t)he * EMB_DIM) + 2 * q;
        va[8] = p[0]; vb[8] = p[1];
    }
    float smin = FLT_MAX, pmin = FLT_MAX;
#pragma unroll
    for (int s = 0; s < SET_SIZE; ++s) {
        float x = dot4f(va[8], va[s]) + dot4f(vb[8], vb[s]);
        x += __shfl_xor(x, 1); x += __shfl_xor(x, 2); x += __shfl_xor(x, 4);
        smin = fminf(smin, x);
    }
#pragma unroll
    for (int s = 0; s < SET_SIZE; ++s) {
#pragma unroll
        for (int t = s; t < SET_SIZE; ++t) {
            float x = dot4f(va[s], va[t]) + dot4f(vb[s], vb[t]);
            x += __shfl_xor(x, 1); x += __shfl_xor(x, 2); x += __shfl_xor(x, 4);
            pmin = fminf(pmin, x);
        }
    }
    float res = (q == 0) ? 1.0f / (1.0f + __expf(-smin))
                         : 1.0f / (1.0f + __expf(-pmin));
    if (q < 2) out[(size_t)grp * 2 + q] = res;
}

extern "C" void kernel_launch(void* const* d_in, const int* in_sizes, int n_in,
                              void* d_out, int out_size, void* d_ws, size_t ws_size,
                              hipStream_t stream) {
    const float* node_emb      = (const float*)d_in[0];
    const float* hyperedge_emb = (const float*)d_in[1];
    const int*   h             = (const int*)d_in[2];
    const int*   X             = (const int*)d_in[3];
    float*       out           = (float*)d_out;

    int n_node_elems = in_sizes[0];  // 6,400,000
    int n_he_elems   = in_sizes[1];  // 3,200,000
    int n_cand       = in_sizes[2];  // 200,000

    size_t need = ((size_t)n_node_elems + (size_t)n_he_elems) * sizeof(__half);
    int block = 256;

    if (ws_size >= need) {
        __half* node_f16 = (__half*)d_ws;
        __half* he_f16   = node_f16 + n_node_elems;

        int n8_node = n_node_elems / 8;
        int n8_he   = n_he_elems / 8;
        int n8_tot  = n8_node + n8_he;
        cvt_both_kernel<<<(n8_tot + block - 1) / block, block, 0, stream>>>(
            node_emb, hyperedge_emb, node_f16, he_f16, n8_node, n8_he);

        // Grid-stride: ~2 candidates per quad so the X-prefetch pipeline has depth.
        const int UNROLL = 2;
        long long total_threads = ((long long)n_cand * 4 + UNROLL - 1) / UNROLL;
        int grid_main = (int)((total_threads + block - 1) / block);
        hyperedge_score_q4<<<grid_main, block, 0, stream>>>(
            node_f16, he_f16, h, X, out, n_cand);
    } else {
        long long total_threads = (long long)n_cand * 8;
        int grid_main = (int)((total_threads + block - 1) / block);
        hyperedge_score_f32<<<grid_main, block, 0, stream>>>(
            node_emb, hyperedge_emb, h, X, out, n_cand);
    }
}

// Round 8
// 114.400 us; speedup vs baseline: 1.0337x; 1.0337x over previous
//
#include <hip/hip_runtime.h>
#include <hip/hip_fp16.h>
#include <math.h>
#include <float.h>

#define SET_SIZE 8
#define EMB_DIM 64
#define NPAIR 36
#define NDOT (SET_SIZE + NPAIR)

typedef _Float16 f16x2 __attribute__((ext_vector_type(2)));

union Frag32 {
    float4 f4[2];   // two 16B raw loads (32B = 16 fp16)
    f16x2  h2[8];   // 16 fp16 elements
};

__device__ __forceinline__ float dot16_f16(const Frag32& a, const Frag32& b) {
    float c = 0.0f;
#pragma unroll
    for (int j = 0; j < 8; ++j)
        c = __builtin_amdgcn_fdot2(a.h2[j], b.h2[j], c, false);
    return c;
}

// Sum across the 4 lanes of a quad using DPP quad_perm (pure VALU, no LDS pipe).
// quad_perm [1,0,3,2] = 0xB1 (xor 1), quad_perm [2,3,0,1] = 0x4E (xor 2).
__device__ __forceinline__ float quad_reduce_add(float x) {
    int t = __builtin_amdgcn_update_dpp(0, __float_as_int(x), 0xB1, 0xF, 0xF, true);
    x += __int_as_float(t);
    t = __builtin_amdgcn_update_dpp(0, __float_as_int(x), 0x4E, 0xF, 0xF, true);
    x += __int_as_float(t);
    return x;
}

// Fused f32 -> f16 conversion for both tables; 8 floats per thread.
__global__ __launch_bounds__(256) void cvt_both_kernel(
    const float* __restrict__ a, const float* __restrict__ b,
    __half* __restrict__ oa, __half* __restrict__ ob, int n8a, int n8b)
{
    int i = blockIdx.x * blockDim.x + threadIdx.x;
    const float* in;
    __half* out;
    int j;
    if (i < n8a) { in = a; out = oa; j = i; }
    else if (i < n8a + n8b) { in = b; out = ob; j = i - n8a; }
    else return;
    const float4* p = (const float4*)in + 2 * (size_t)j;
    float4 x = p[0], y = p[1];
    union { __half2 h2[4]; float4 f4; } u;
    u.h2[0] = __floats2half2_rn(x.x, x.y);
    u.h2[1] = __floats2half2_rn(x.z, x.w);
    u.h2[2] = __floats2half2_rn(y.x, y.y);
    u.h2[3] = __floats2half2_rn(y.z, y.w);
    ((float4*)out)[j] = u.f4;
}

// 4 lanes per candidate; lane q owns 32B of each 128B fp16 row. Each dot is
// computed, quad-reduced via DPP, and folded into the running min IMMEDIATELY,
// so liveness is just the 9 row fragments (72 VGPRs) + 2 running mins.
// One candidate per quad, no grid-stride: maximal independent waves = maximal
// memory-level parallelism (R7's software pipeline regressed by serializing
// the next gather behind the current dot phase).
__global__ __launch_bounds__(256, 5) void hyperedge_score_q4(
    const __half* __restrict__ node_f16,   // [N_NODES, 64]
    const __half* __restrict__ he_f16,     // [N_HYPEREDGES, 64]
    const int*    __restrict__ h,          // [E]
    const int*    __restrict__ X,          // [E, 8]
    float*        __restrict__ out,        // [E, 2]
    int n_cand)
{
    int tid = blockIdx.x * blockDim.x + threadIdx.x;
    int grp = tid >> 2;   // candidate id
    int q   = tid & 3;    // lane within quad
    if (grp >= n_cand) return;

    const int4* Xv = (const int4*)(X + (size_t)grp * SET_SIZE);
    int4 x0 = Xv[0];
    int4 x1 = Xv[1];
    int he = h[grp];
    int idx[SET_SIZE] = {x0.x, x0.y, x0.z, x0.w, x1.x, x1.y, x1.z, x1.w};

    Frag32 v[9];
#pragma unroll
    for (int r = 0; r < SET_SIZE; ++r) {
        const float4* p = (const float4*)(node_f16 + (size_t)idx[r] * EMB_DIM);
        v[r].f4[0] = p[q];
        v[r].f4[1] = p[q + 4];
    }
    {
        const float4* p = (const float4*)(he_f16 + (size_t)he * EMB_DIM);
        v[8].f4[0] = p[q];
        v[8].f4[1] = p[q + 4];
    }

    // Star dots: immediate reduce + min-fold.
    float smin = FLT_MAX;
#pragma unroll
    for (int s = 0; s < SET_SIZE; ++s) {
        float d = quad_reduce_add(dot16_f16(v[8], v[s]));
        smin = fminf(smin, d);
    }

    // Pair dots (upper triangle incl diagonal): immediate reduce + min-fold.
    float pmin = FLT_MAX;
#pragma unroll
    for (int s = 0; s < SET_SIZE; ++s) {
#pragma unroll
        for (int t = s; t < SET_SIZE; ++t) {
            float d = quad_reduce_add(dot16_f16(v[s], v[t]));
            pmin = fminf(pmin, d);
        }
    }

    // sigmoid is monotonic: min(sigmoid(x)) == sigmoid(min(x))
    float res = (q == 0) ? 1.0f / (1.0f + __expf(-smin))
                         : 1.0f / (1.0f + __expf(-pmin));
    if (q < 2) out[(size_t)grp * 2 + q] = res;
}

// ---- f32 fallback (R2 structure) if workspace is too small ----
__device__ __forceinline__ float dot4f(float4 a, float4 b) {
    return fmaf(a.x, b.x, fmaf(a.y, b.y, fmaf(a.z, b.z, a.w * b.w)));
}

__global__ __launch_bounds__(256) void hyperedge_score_f32(
    const float* __restrict__ node_emb, const float* __restrict__ hyperedge_emb,
    const int* __restrict__ h, const int* __restrict__ X,
    float* __restrict__ out, int n_cand)
{
    int tid = blockIdx.x * blockDim.x + threadIdx.x;
    int grp = tid >> 3;
    int q   = tid & 7;
    if (grp >= n_cand) return;
    const int4* Xv = (const int4*)(X + (size_t)grp * SET_SIZE);
    int4 x0 = Xv[0]; int4 x1 = Xv[1];
    int he = h[grp];
    int idx[SET_SIZE] = {x0.x, x0.y, x0.z, x0.w, x1.x, x1.y, x1.z, x1.w};
    float4 va[9], vb[9];
#pragma unroll
    for (int r = 0; r < SET_SIZE; ++r) {
        const float4* p = (const float4*)(node_emb + (size_t)idx[r] * EMB_DIM) + 2 * q;
        va[r] = p[0]; vb[r] = p[1];
    }
    {
        const float4* p = (const float4*)(hyperedge_emb + (size_t)he * EMB_DIM) + 2 * q;
        va[8] = p[0]; vb[8] = p[1];
    }
    float smin = FLT_MAX, pmin = FLT_MAX;
#pragma unroll
    for (int s = 0; s < SET_SIZE; ++s) {
        float x = dot4f(va[8], va[s]) + dot4f(vb[8], vb[s]);
        x += __shfl_xor(x, 1); x += __shfl_xor(x, 2); x += __shfl_xor(x, 4);
        smin = fminf(smin, x);
    }
#pragma unroll
    for (int s = 0; s < SET_SIZE; ++s) {
#pragma unroll
        for (int t = s; t < SET_SIZE; ++t) {
            float x = dot4f(va[s], va[t]) + dot4f(vb[s], vb[t]);
            x += __shfl_xor(x, 1); x += __shfl_xor(x, 2); x += __shfl_xor(x, 4);
            pmin = fminf(pmin, x);
        }
    }
    float res = (q == 0) ? 1.0f / (1.0f + __expf(-smin))
                         : 1.0f / (1.0f + __expf(-pmin));
    if (q < 2) out[(size_t)grp * 2 + q] = res;
}

extern "C" void kernel_launch(void* const* d_in, const int* in_sizes, int n_in,
                              void* d_out, int out_size, void* d_ws, size_t ws_size,
                              hipStream_t stream) {
    const float* node_emb      = (const float*)d_in[0];
    const float* hyperedge_emb = (const float*)d_in[1];
    const int*   h             = (const int*)d_in[2];
    const int*   X             = (const int*)d_in[3];
    float*       out           = (float*)d_out;

    int n_node_elems = in_sizes[0];  // 6,400,000
    int n_he_elems   = in_sizes[1];  // 3,200,000
    int n_cand       = in_sizes[2];  // 200,000

    size_t need = ((size_t)n_node_elems + (size_t)n_he_elems) * sizeof(__half);
    int block = 256;

    if (ws_size >= need) {
        __half* node_f16 = (__half*)d_ws;
        __half* he_f16   = node_f16 + n_node_elems;

        int n8_node = n_node_elems / 8;
        int n8_he   = n_he_elems / 8;
        int n8_tot  = n8_node + n8_he;
        cvt_both_kernel<<<(n8_tot + block - 1) / block, block, 0, stream>>>(
            node_emb, hyperedge_emb, node_f16, he_f16, n8_node, n8_he);

        long long total_threads = (long long)n_cand * 4;
        int grid_main = (int)((total_threads + block - 1) / block);
        hyperedge_score_q4<<<grid_main, block, 0, stream>>>(
            node_f16, he_f16, h, X, out, n_cand);
    } else {
        long long total_threads = (long long)n_cand * 8;
        int grid_main = (int)((total_threads + block - 1) / block);
        hyperedge_score_f32<<<grid_main, block, 0, stream>>>(
            node_emb, hyperedge_emb, h, X, out, n_cand);
    }
}